// Round 1
// baseline (20932.886 us; speedup 1.0000x reference)
//
#include <hip/hip_runtime.h>

// Bidirectional LSTM, B=64 S=256 I=H=512, f32 in/out.
// Persistent dataflow kernel: 256 WGs = 2 dirs x 4 batch-groups(16 rows) x 32 col-slices(16 h-cols).
// Weights (fp16, MFMA-frag-packed) LDS-resident; cross-WG h exchange via device-scope flags.

typedef float    f32x4 __attribute__((ext_vector_type(4)));
typedef _Float16 half8 __attribute__((ext_vector_type(8)));

#define NB 64
#define NS 256
#define NI 512
#define NH 512

__device__ inline f32x4 zero4() { f32x4 v; v[0]=0.f; v[1]=0.f; v[2]=0.f; v[3]=0.f; return v; }

// ---------------- prep kernels ----------------

// x f32 -> fp16, 8 elements/thread. grid: 4096x256 (=8388608 elems)
__global__ void conv_x(const float* __restrict__ x, _Float16* __restrict__ xb) {
    const int i = blockIdx.x * 256 + threadIdx.x;
    const float4 a = ((const float4*)x)[2*i];
    const float4 b = ((const float4*)x)[2*i+1];
    half8 o;
    o[0]=(_Float16)a.x; o[1]=(_Float16)a.y; o[2]=(_Float16)a.z; o[3]=(_Float16)a.w;
    o[4]=(_Float16)b.x; o[5]=(_Float16)b.y; o[6]=(_Float16)b.z; o[7]=(_Float16)b.w;
    ((half8*)xb)[i] = o;
}

// Pack W (I+H,H) f32 into fp16 MFMA-B-frag order:
// WP[d][s][p][kk][g][l][j] = W_{d,g}[p*512 + kk*32 + (l>>4)*8 + j][s*16 + (l&15)]
// one thread per (d,s,p,kk,g,l) writes 8 fp16 (16B). grid: 2048x256 (=524288)
__global__ void pack_w(const float* __restrict__ Wi_f, const float* __restrict__ Wf_f,
                       const float* __restrict__ Wo_f, const float* __restrict__ Wc_f,
                       const float* __restrict__ Wi_b, const float* __restrict__ Wf_b,
                       const float* __restrict__ Wo_b, const float* __restrict__ Wc_b,
                       _Float16* __restrict__ WP) {
    const int idx = blockIdx.x * 256 + threadIdx.x;
    const int l  = idx & 63;
    const int g  = (idx >> 6) & 3;
    const int kk = (idx >> 8) & 15;
    const int p  = (idx >> 12) & 1;
    const int s  = (idx >> 13) & 31;
    const int d  = (idx >> 18) & 1;
    const float* W;
    if (d == 0) W = (g==0) ? Wi_f : (g==1) ? Wf_f : (g==2) ? Wo_f : Wc_f;
    else        W = (g==0) ? Wi_b : (g==1) ? Wf_b : (g==2) ? Wo_b : Wc_b;
    const int r0 = p*512 + kk*32 + (l >> 4)*8;
    const int c  = s*16 + (l & 15);
    half8 v;
    #pragma unroll
    for (int j = 0; j < 8; ++j) v[j] = (_Float16)W[(size_t)(r0 + j)*NH + c];
    *(half8*)(WP + (size_t)idx*8) = v;
}

// biasP[d][g][c]. grid: 16x256 (=4096)
__global__ void pack_bias(const float* __restrict__ bi_f, const float* __restrict__ bf_f,
                          const float* __restrict__ bo_f, const float* __restrict__ bc_f,
                          const float* __restrict__ bi_b, const float* __restrict__ bf_b,
                          const float* __restrict__ bo_b, const float* __restrict__ bc_b,
                          float* __restrict__ biasP) {
    const int i = blockIdx.x * 256 + threadIdx.x;
    const int c = i & 511, g = (i >> 9) & 3, d = (i >> 11) & 1;
    const float* b;
    if (d == 0) b = (g==0) ? bi_f : (g==1) ? bf_f : (g==2) ? bo_f : bc_f;
    else        b = (g==0) ? bi_b : (g==1) ? bf_b : (g==2) ? bo_b : bc_b;
    biasP[i] = b[c];
}

// ---------------- main persistent scan kernel ----------------
// grid 256 x 256. LDS: 128KiB packed weights + 16KiB reduce buffer = 144KiB -> 1 WG/CU.

__global__ __launch_bounds__(256) void lstm_scan(
    const _Float16* __restrict__ xb,     // [64][256][512]
    const _Float16* __restrict__ WP,     // [2][32][2][16][4][64][8]
    const float*    __restrict__ biasP,  // [2][4][512]
    _Float16*       __restrict__ hglob,  // [2][4][2][16][512]
    unsigned*       __restrict__ flags,  // [2][4][32]
    float*          __restrict__ out)    // [64][256][1024]
{
    __shared__ char  ldsw[131072];
    __shared__ float redb[4][4][64][4];

    const int wg  = blockIdx.x;
    const int d   = wg >> 7;          // direction
    const int bg  = (wg >> 5) & 3;    // batch group (16 rows)
    const int s   = wg & 31;          // column slice (16 h-cols)
    const int tid = threadIdx.x;
    const int w   = tid >> 6;         // wave 0..3 (K-split)
    const int l   = tid & 63;

    // stage packed weight slice (128 KiB) into LDS, linear copy
    {
        const uint4* src = (const uint4*)(WP + (size_t)(d*32 + s)*65536);
        uint4* dst = (uint4*)ldsw;
        #pragma unroll
        for (int i = 0; i < 32; ++i) dst[tid + i*256] = src[tid + i*256];
    }
    __syncthreads();

    float bias0 = 0.f, bias1 = 0.f, bias2 = 0.f, bias3 = 0.f;
    if (w == 0) {
        const int c = s*16 + (l & 15);
        bias0 = biasP[(d*4 + 0)*512 + c];
        bias1 = biasP[(d*4 + 1)*512 + c];
        bias2 = biasP[(d*4 + 2)*512 + c];
        bias3 = biasP[(d*4 + 3)*512 + c];
    }

    f32x4 acc[4];
    #pragma unroll
    for (int g = 0; g < 4; ++g) acc[g] = zero4();
    f32x4 cst = zero4();                  // cell state (wave 0 only)

    unsigned fc[8] = {0,0,0,0,0,0,0,0};   // cached flag values (monotonic)
    unsigned* myflags = flags + (d*4 + bg)*32;
    bool dead = false;                    // sticky guard-trip (anti-hang)

    const int arow = bg*16 + (l & 15);    // A-frag row = batch row
    const int kof  = (l >> 4) * 8;        // A/B frag k sub-offset
    const int kk0  = w * 4;               // this wave's first k-chunk

    for (int t = 0; t < NS; ++t) {
        const int u = d ? (NS - 1 - t) : t;   // time index in x/out

        // ---- issue x A-frag loads (no dependency) ----
        const _Float16* xp = xb + ((size_t)arow*NS + u)*NI + kof;
        half8 af[4];
        #pragma unroll
        for (int c = 0; c < 4; ++c) af[c] = *(const half8*)(xp + (kk0 + c)*32);

        half8 ah[4];
        if (t > 0) {
            // wait for the 8 producer slices covering our h K-range
            #pragma unroll
            for (int q = 0; q < 8; ++q) {
                if (!dead && fc[q] < (unsigned)t) {
                    int guard = 0; unsigned v;
                    do {
                        v = __hip_atomic_load(&myflags[w*8 + q], __ATOMIC_ACQUIRE,
                                              __HIP_MEMORY_SCOPE_AGENT);
                        if (++guard > (1 << 22)) { dead = true; break; }
                    } while (v < (unsigned)t);
                    fc[q] = v;
                }
            }
            const _Float16* hp = hglob +
                ((size_t)((d*4 + bg)*2 + (t & 1))*16 + (l & 15))*NH + kof;
            #pragma unroll
            for (int c = 0; c < 4; ++c) ah[c] = *(const half8*)(hp + (kk0 + c)*32);
        }

        // ---- x-part MFMAs (hide h wait/load latency behind these) ----
        #pragma unroll
        for (int c = 0; c < 4; ++c) {
            #pragma unroll
            for (int g = 0; g < 4; ++g) {
                const half8 b = *(const half8*)(ldsw + ((((kk0 + c)*4 + g) << 10) | (l << 4)));
                acc[g] = __builtin_amdgcn_mfma_f32_16x16x32_f16(af[c], b, acc[g], 0, 0, 0);
            }
        }
        // ---- h-part MFMAs ----
        if (t > 0) {
            #pragma unroll
            for (int c = 0; c < 4; ++c) {
                #pragma unroll
                for (int g = 0; g < 4; ++g) {
                    const half8 b = *(const half8*)(ldsw + ((((16 + kk0 + c)*4 + g) << 10) | (l << 4)));
                    acc[g] = __builtin_amdgcn_mfma_f32_16x16x32_f16(ah[c], b, acc[g], 0, 0, 0);
                }
            }
        }

        // ---- K-reduction across waves + epilogue (wave 0) ----
        __syncthreads();   // A: prev-step wave0 reduce-buffer reads are done
        if (w != 0) {
            #pragma unroll
            for (int g = 0; g < 4; ++g) *(f32x4*)&redb[w][g][l][0] = acc[g];
        }
        __syncthreads();   // B: partials visible
        if (w == 0) {
            #pragma unroll
            for (int g = 0; g < 4; ++g) {
                #pragma unroll
                for (int wv = 1; wv < 4; ++wv) acc[g] += *(f32x4*)&redb[wv][g][l][0];
            }
            f32x4 hv;
            #pragma unroll
            for (int r = 0; r < 4; ++r) {
                const float ig = 1.f / (1.f + __expf(-(acc[0][r] + bias0)));
                const float fg = 1.f / (1.f + __expf(-(acc[1][r] + bias1)));
                const float og = 1.f / (1.f + __expf(-(acc[2][r] + bias2)));
                const float gv = acc[3][r] + bias3;
                const float gg = 1.f - 2.f / (__expf(2.f*gv) + 1.f);        // tanh
                cst[r] = fg*cst[r] + ig*gg;
                hv[r]  = og * (1.f - 2.f / (__expf(2.f*cst[r]) + 1.f));
            }
            const int colg = s*16 + (l & 15);
            _Float16* hw = hglob + ((size_t)((d*4 + bg)*2 + ((t + 1) & 1))*16)*NH;
            #pragma unroll
            for (int r = 0; r < 4; ++r) {
                const int brow = (l >> 4)*4 + r;
                out[((size_t)(bg*16 + brow)*NS + u)*1024 + (d << 9) + colg] = hv[r];
                hw[brow*NH + colg] = (_Float16)hv[r];
            }
            __threadfence();   // make h stores agent-visible before flag
            __hip_atomic_store(&myflags[s], (unsigned)(t + 1), __ATOMIC_RELEASE,
                               __HIP_MEMORY_SCOPE_AGENT);
        }
        #pragma unroll
        for (int g = 0; g < 4; ++g) acc[g] = zero4();
    }
}

// ---------------- launch ----------------

extern "C" void kernel_launch(void* const* d_in, const int* in_sizes, int n_in,
                              void* d_out, int out_size, void* d_ws, size_t ws_size,
                              hipStream_t stream) {
    const float* x = (const float*)d_in[0];
    char* ws = (char*)d_ws;
    _Float16* xb    = (_Float16*)ws;                                   // 16 MiB
    _Float16* WP    = (_Float16*)(ws + (16u << 20));                   // 8 MiB
    float*    biasP = (float*)(ws + (24u << 20));                      // 16 KiB
    _Float16* hglb  = (_Float16*)(ws + (24u << 20) + (64u << 10));     // 256 KiB
    unsigned* flags = (unsigned*)(ws + (24u << 20) + (64u << 10) + (256u << 10)); // 1 KiB

    hipMemsetAsync(flags, 0, 1024, stream);
    conv_x<<<4096, 256, 0, stream>>>(x, xb);
    // gate order g: 0=i(Wi) 1=f(Wf) 2=o(Wo) 3=g(Wc)
    pack_w<<<2048, 256, 0, stream>>>(
        (const float*)d_in[1],  (const float*)d_in[3],  (const float*)d_in[7],  (const float*)d_in[5],
        (const float*)d_in[9],  (const float*)d_in[11], (const float*)d_in[15], (const float*)d_in[13], WP);
    pack_bias<<<16, 256, 0, stream>>>(
        (const float*)d_in[2],  (const float*)d_in[4],  (const float*)d_in[8],  (const float*)d_in[6],
        (const float*)d_in[10], (const float*)d_in[12], (const float*)d_in[16], (const float*)d_in[14], biasP);
    lstm_scan<<<256, 256, 0, stream>>>(xb, WP, biasP, hglb, flags, (float*)d_out);
}

// Round 3
// 1198.189 us; speedup vs baseline: 17.4704x; 17.4704x over previous
//
#include <hip/hip_runtime.h>

// Bidirectional LSTM, B=64 S=256 I=H=512, f32 in/out.
// Persistent dataflow kernel: 256 WGs = 2 dirs x 4 batch-groups(16 rows) x 32 col-slices(16 h-cols).
// Weights (fp16, MFMA-frag-packed) LDS-resident.
// Cross-WG h exchange via RELAXED agent-scope atomics (per-access coherence at IF$, no
// buffer_inv / buffer_wbl2 cache-wide ops). Ordering: s_waitcnt vmcnt(0) between h stores
// and the (agent-scope, relaxed) flag store. Round-2 bug was a workgroup-scope flag store
// that stayed in the producer XCD's L2 — invisible cross-XCD.

typedef float    f32x4 __attribute__((ext_vector_type(4)));
typedef _Float16 half8 __attribute__((ext_vector_type(8)));
typedef unsigned long long u64;

#define NB 64
#define NS 256
#define NI 512
#define NH 512

__device__ inline f32x4 zero4() { f32x4 v; v[0]=0.f; v[1]=0.f; v[2]=0.f; v[3]=0.f; return v; }

// ---------------- prep kernels ----------------

// x f32 -> fp16, 8 elements/thread. grid: 4096x256
__global__ void conv_x(const float* __restrict__ x, _Float16* __restrict__ xb) {
    const int i = blockIdx.x * 256 + threadIdx.x;
    const float4 a = ((const float4*)x)[2*i];
    const float4 b = ((const float4*)x)[2*i+1];
    half8 o;
    o[0]=(_Float16)a.x; o[1]=(_Float16)a.y; o[2]=(_Float16)a.z; o[3]=(_Float16)a.w;
    o[4]=(_Float16)b.x; o[5]=(_Float16)b.y; o[6]=(_Float16)b.z; o[7]=(_Float16)b.w;
    ((half8*)xb)[i] = o;
}

// Pack W (I+H,H) f32 into fp16 MFMA-B-frag order:
// WP[d][s][p][kk][g][l][j] = W_{d,g}[p*512 + kk*32 + (l>>4)*8 + j][s*16 + (l&15)]
__global__ void pack_w(const float* __restrict__ Wi_f, const float* __restrict__ Wf_f,
                       const float* __restrict__ Wo_f, const float* __restrict__ Wc_f,
                       const float* __restrict__ Wi_b, const float* __restrict__ Wf_b,
                       const float* __restrict__ Wo_b, const float* __restrict__ Wc_b,
                       _Float16* __restrict__ WP) {
    const int idx = blockIdx.x * 256 + threadIdx.x;
    const int l  = idx & 63;
    const int g  = (idx >> 6) & 3;
    const int kk = (idx >> 8) & 15;
    const int p  = (idx >> 12) & 1;
    const int s  = (idx >> 13) & 31;
    const int d  = (idx >> 18) & 1;
    const float* W;
    if (d == 0) W = (g==0) ? Wi_f : (g==1) ? Wf_f : (g==2) ? Wo_f : Wc_f;
    else        W = (g==0) ? Wi_b : (g==1) ? Wf_b : (g==2) ? Wo_b : Wc_b;
    const int r0 = p*512 + kk*32 + (l >> 4)*8;
    const int c  = s*16 + (l & 15);
    half8 v;
    #pragma unroll
    for (int j = 0; j < 8; ++j) v[j] = (_Float16)W[(size_t)(r0 + j)*NH + c];
    *(half8*)(WP + (size_t)idx*8) = v;
}

// biasP[d][g][c]
__global__ void pack_bias(const float* __restrict__ bi_f, const float* __restrict__ bf_f,
                          const float* __restrict__ bo_f, const float* __restrict__ bc_f,
                          const float* __restrict__ bi_b, const float* __restrict__ bf_b,
                          const float* __restrict__ bo_b, const float* __restrict__ bc_b,
                          float* __restrict__ biasP) {
    const int i = blockIdx.x * 256 + threadIdx.x;
    const int c = i & 511, g = (i >> 9) & 3, d = (i >> 11) & 1;
    const float* b;
    if (d == 0) b = (g==0) ? bi_f : (g==1) ? bf_f : (g==2) ? bo_f : bc_f;
    else        b = (g==0) ? bi_b : (g==1) ? bf_b : (g==2) ? bo_b : bc_b;
    biasP[i] = b[c];
}

// ---------------- main persistent scan kernel ----------------
// grid 256 x 256. LDS: 128KiB packed weights + 16KiB reduce buffer -> 1 WG/CU.

__global__ __launch_bounds__(256) void lstm_scan(
    const _Float16* __restrict__ xb,     // [64][256][512]
    const _Float16* __restrict__ WP,     // [2][32][2][16][4][64][8]
    const float*    __restrict__ biasP,  // [2][4][512]
    _Float16*       __restrict__ hglob,  // [2][4][2][16][512]  (double-buffered h, fp16)
    unsigned*       __restrict__ flags,  // [2][4][32]
    float*          __restrict__ out)    // [64][256][1024]
{
    __shared__ char  ldsw[131072];
    __shared__ float redb[4][4][64][4];

    const int wg  = blockIdx.x;
    const int d   = wg >> 7;          // direction
    const int bg  = (wg >> 5) & 3;    // batch group (16 rows)
    const int s   = wg & 31;          // column slice (16 h-cols)
    const int tid = threadIdx.x;
    const int w   = tid >> 6;         // wave 0..3 (K-split)
    const int l   = tid & 63;

    // stage packed weight slice (128 KiB) into LDS
    {
        const uint4* src = (const uint4*)(WP + (size_t)(d*32 + s)*65536);
        uint4* dst = (uint4*)ldsw;
        #pragma unroll
        for (int i = 0; i < 32; ++i) dst[tid + i*256] = src[tid + i*256];
    }
    __syncthreads();

    float bias0 = 0.f, bias1 = 0.f, bias2 = 0.f, bias3 = 0.f;
    if (w == 0) {
        const int c = s*16 + (l & 15);
        bias0 = biasP[(d*4 + 0)*512 + c];
        bias1 = biasP[(d*4 + 1)*512 + c];
        bias2 = biasP[(d*4 + 2)*512 + c];
        bias3 = biasP[(d*4 + 3)*512 + c];
    }

    f32x4 acc[4];
    #pragma unroll
    for (int g = 0; g < 4; ++g) acc[g] = zero4();
    f32x4 cst = zero4();                  // cell state (wave 0 only)

    unsigned* myflags = flags + (d*4 + bg)*32;
    bool dead = false;                    // sticky guard-trip (anti-hang)

    const int arow = bg*16 + (l & 15);    // A-frag row = batch row
    const int kof  = (l >> 4) * 8;        // A/B frag k sub-offset
    const int kk0  = w * 4;               // this wave's first k-chunk
    const int fidx = w*8 + (l & 7);       // flag this lane polls (8 producers / wave, parallel)

    for (int t = 0; t < NS; ++t) {
        const int u = d ? (NS - 1 - t) : t;   // time index in x/out

        // ---- x A-frag loads + x-part MFMAs (independent of h; overlap producer latency) ----
        const _Float16* xp = xb + ((size_t)arow*NS + u)*NI + kof;
        half8 af[4];
        #pragma unroll
        for (int c = 0; c < 4; ++c) af[c] = *(const half8*)(xp + (kk0 + c)*32);
        #pragma unroll
        for (int c = 0; c < 4; ++c) {
            #pragma unroll
            for (int g = 0; g < 4; ++g) {
                const half8 b = *(const half8*)(ldsw + ((((kk0 + c)*4 + g) << 10) | (l << 4)));
                acc[g] = __builtin_amdgcn_mfma_f32_16x16x32_f16(af[c], b, acc[g], 0, 0, 0);
            }
        }

        // ---- h-part: parallel flag wait (relaxed agent atomics), h loads, MFMAs ----
        if (t > 0) {
            const unsigned tgt = (unsigned)t;
            if (!dead) {
                int guard = 0;
                unsigned v;
                do {
                    v = __hip_atomic_load(&myflags[fidx], __ATOMIC_RELAXED,
                                          __HIP_MEMORY_SCOPE_AGENT);
                    if (++guard > (1 << 20)) { dead = true; break; }
                } while (__any(v < tgt));
            }
            const _Float16* hp = hglob +
                ((size_t)((d*4 + bg)*2 + (t & 1))*16 + (l & 15))*NH + kof;
            union { u64 q[2]; half8 h; } hu;
            #pragma unroll
            for (int c = 0; c < 4; ++c) {
                const u64* p64 = (const u64*)(hp + (kk0 + c)*32);
                hu.q[0] = __hip_atomic_load(p64,     __ATOMIC_RELAXED, __HIP_MEMORY_SCOPE_AGENT);
                hu.q[1] = __hip_atomic_load(p64 + 1, __ATOMIC_RELAXED, __HIP_MEMORY_SCOPE_AGENT);
                const half8 ah = hu.h;
                #pragma unroll
                for (int g = 0; g < 4; ++g) {
                    const half8 b = *(const half8*)(ldsw + ((((16 + kk0 + c)*4 + g) << 10) | (l << 4)));
                    acc[g] = __builtin_amdgcn_mfma_f32_16x16x32_f16(ah, b, acc[g], 0, 0, 0);
                }
            }
        }

        // ---- K-reduction across waves + epilogue (wave 0) ----
        __syncthreads();   // A: prev-step wave0 reduce-buffer reads are done
        if (w != 0) {
            #pragma unroll
            for (int g = 0; g < 4; ++g) *(f32x4*)&redb[w][g][l][0] = acc[g];
        }
        __syncthreads();   // B: partials visible
        if (w == 0) {
            #pragma unroll
            for (int g = 0; g < 4; ++g) {
                #pragma unroll
                for (int wv = 1; wv < 4; ++wv) acc[g] += *(f32x4*)&redb[wv][g][l][0];
            }
            f32x4 hv;
            #pragma unroll
            for (int r = 0; r < 4; ++r) {
                const float ig = 1.f / (1.f + __expf(-(acc[0][r] + bias0)));
                const float fg = 1.f / (1.f + __expf(-(acc[1][r] + bias1)));
                const float og = 1.f / (1.f + __expf(-(acc[2][r] + bias2)));
                const float gv = acc[3][r] + bias3;
                const float gg = 1.f - 2.f / (__expf(2.f*gv) + 1.f);        // tanh
                cst[r] = fg*cst[r] + ig*gg;
                hv[r]  = og * (1.f - 2.f / (__expf(2.f*cst[r]) + 1.f));
            }
            const int colg = s*16 + (l & 15);
            _Float16* hw = hglob + ((size_t)((d*4 + bg)*2 + ((t + 1) & 1))*16)*NH;
            // h stores: lane-paired u32 relaxed agent atomics (device-coherent at IF$)
            #pragma unroll
            for (int r = 0; r < 4; ++r) {
                const int brow = (l >> 4)*4 + r;
                const unsigned short hb = __builtin_bit_cast(unsigned short, (_Float16)hv[r]);
                const unsigned other = (unsigned)__shfl_xor((int)(unsigned)hb, 1, 64) & 0xffffu;
                if (!(l & 1)) {
                    const unsigned val = (unsigned)hb | (other << 16);
                    __hip_atomic_store((unsigned*)(hw + brow*NH + colg), val,
                                       __ATOMIC_RELAXED, __HIP_MEMORY_SCOPE_AGENT);
                }
            }
            // release ordering for the atomic stream: wait h store-acks at the coherence
            // point, THEN publish the flag — also agent-scope so it is visible cross-XCD.
            asm volatile("s_waitcnt vmcnt(0)" ::: "memory");
            if (l == 0)
                __hip_atomic_store(&myflags[s], (unsigned)(t + 1),
                                   __ATOMIC_RELAXED, __HIP_MEMORY_SCOPE_AGENT);
            // out stores (normal cached f32) issued after the flag so vmcnt(0) skips them
            #pragma unroll
            for (int r = 0; r < 4; ++r) {
                const int brow = (l >> 4)*4 + r;
                out[((size_t)(bg*16 + brow)*NS + u)*1024 + (d << 9) + colg] = hv[r];
            }
        }
        #pragma unroll
        for (int g = 0; g < 4; ++g) acc[g] = zero4();
    }
}

// ---------------- launch ----------------

extern "C" void kernel_launch(void* const* d_in, const int* in_sizes, int n_in,
                              void* d_out, int out_size, void* d_ws, size_t ws_size,
                              hipStream_t stream) {
    const float* x = (const float*)d_in[0];
    char* ws = (char*)d_ws;
    _Float16* xb    = (_Float16*)ws;                                   // 16 MiB
    _Float16* WP    = (_Float16*)(ws + (16u << 20));                   // 8 MiB
    float*    biasP = (float*)(ws + (24u << 20));                      // 16 KiB
    _Float16* hglb  = (_Float16*)(ws + (24u << 20) + (64u << 10));     // 256 KiB
    unsigned* flags = (unsigned*)(ws + (24u << 20) + (64u << 10) + (256u << 10)); // 1 KiB

    hipMemsetAsync(flags, 0, 1024, stream);
    conv_x<<<4096, 256, 0, stream>>>(x, xb);
    // gate order g: 0=i(Wi) 1=f(Wf) 2=o(Wo) 3=g(Wc)
    pack_w<<<2048, 256, 0, stream>>>(
        (const float*)d_in[1],  (const float*)d_in[3],  (const float*)d_in[7],  (const float*)d_in[5],
        (const float*)d_in[9],  (const float*)d_in[11], (const float*)d_in[15], (const float*)d_in[13], WP);
    pack_bias<<<16, 256, 0, stream>>>(
        (const float*)d_in[2],  (const float*)d_in[4],  (const float*)d_in[8],  (const float*)d_in[6],
        (const float*)d_in[10], (const float*)d_in[12], (const float*)d_in[16], (const float*)d_in[14], biasP);
    lstm_scan<<<256, 256, 0, stream>>>(xb, WP, biasP, hglb, flags, (float*)d_out);
}